// Round 1
// baseline (2292.597 us; speedup 1.0000x reference)
//
#include <hip/hip_runtime.h>
#include <hip/hip_fp16.h>
#include <cstdint>
#include <cstddef>

// Problem constants (fixed by the reference)
#define HIDDEN 4096
#define INTER  11008
#define NTOK   4096          // B*S = 4*1024
#define NG1    (HIDDEN/64)   // 64 groups along hidden
#define NG2    (INTER/64)    // 172 groups along inter

typedef _Float16 f16;
typedef _Float16 f16x8 __attribute__((ext_vector_type(8)));
typedef float    f32x4 __attribute__((ext_vector_type(4)));

// ---- async global->LDS, 16B per lane (dest must be wave-uniform base + lane*16)
__device__ __forceinline__ void g2lds16(const void* g, void* l) {
  __builtin_amdgcn_global_load_lds(
      (const __attribute__((address_space(1))) uint32_t*)g,
      (__attribute__((address_space(3))) uint32_t*)l, 16, 0, 0);
}

// ---- dequant one packed byte-in-dword -> 2 f16 weights: w = (q - z) * s
// b in [0,256): hi nibble = k even, lo nibble = k odd.
// f16 trick: 0x6400|q == (half)(1024+q) exactly; subtract 1024 exactly, then
// fused (q - z)*s = q*s + (-z*s) in one pk_fma (no cancellation blowup).
__device__ __forceinline__ uint32_t dq2(uint32_t b, __half2 s2, __half2 nzs) {
  uint32_t qb = 0x64006400u | (b >> 4) | ((b & 0xFu) << 16);
  __half2 hq = __builtin_bit_cast(__half2, qb);
  __half2 t  = __hsub2(hq, __builtin_bit_cast(__half2, 0x64006400u));
  __half2 wv = __hfma2(t, s2, nzs);
  return __builtin_bit_cast(uint32_t, wv);
}

// ---------------------------------------------------------------- x: fp32->f16
__global__ __launch_bounds__(256) void cvt_x(const float* __restrict__ x,
                                             f16* __restrict__ xh) {
  size_t i = ((size_t)blockIdx.x * 256 + threadIdx.x) * 8;
  float4 a = *(const float4*)(x + i);
  float4 b = *(const float4*)(x + i + 4);
  f16x8 o = {(f16)a.x, (f16)a.y, (f16)a.z, (f16)a.w,
             (f16)b.x, (f16)b.y, (f16)b.z, (f16)b.w};
  *(f16x8*)(xh + i) = o;
}

// -------------------------------------------- GEMM1: h = silu(x Wg^T) * (x Wu^T)
// Block tile: 128 (M) x 64 (N) for BOTH gate and up (shared A staging).
// 4 waves in 2x2; each wave: 64x32 per matrix -> 4x2 frags of 16x16, dual acc.
// BK=64 = one quant group. LDS: A 16KB + Bg 8KB + Bu 8KB = 32KB.
__global__ __launch_bounds__(256) void gemm_gateup(
    const f16* __restrict__ xh,
    const uint32_t* __restrict__ gq, const uint32_t* __restrict__ uq,
    const float* __restrict__ gs, const float* __restrict__ gz,
    const float* __restrict__ us, const float* __restrict__ uz,
    f16* __restrict__ h) {
  __shared__ f16 lA[128 * 64];
  __shared__ f16 lBg[64 * 64];
  __shared__ f16 lBu[64 * 64];
  const int tid = threadIdx.x, lane = tid & 63, wave = tid >> 6;
  const int bn = blockIdx.x, bm = blockIdx.y;      // bn<172, bm<32
  const int wm = wave >> 1, wn = wave & 1;

  f32x4 accg[4][2] = {};
  f32x4 accu[4][2] = {};

  for (int kt = 0; kt < NG1; ++kt) {
    __syncthreads();  // previous tile fully consumed
    // ---- A staging: 128x64 f16, chunk c = i*256+tid, row=c>>3, k8=c&7.
    // XOR-swizzle applied on the GLOBAL side (LDS dest must stay linear).
#pragma unroll
    for (int i = 0; i < 4; ++i) {
      int c = i * 256 + tid;
      int row = c >> 3, k8 = c & 7, k8s = k8 ^ (row & 7);
      const f16* gp = xh + (size_t)(bm * 128 + row) * HIDDEN + kt * 64 + k8s * 8;
      g2lds16(gp, (char*)lA + (size_t)c * 16);
    }
    // ---- B staging + dequant: i=0,1 -> gate ; i=2,3 -> up
#pragma unroll
    for (int i = 0; i < 4; ++i) {
      const uint32_t* q = (i < 2) ? gq : uq;
      const float* sp = (i < 2) ? gs : us;
      const float* zp = (i < 2) ? gz : uz;
      f16* lb = (i < 2) ? lBg : lBu;
      int c = (i & 1) * 256 + tid;          // 0..511
      int row = c >> 3, k8 = c & 7;
      int grow = bn * 64 + row;
      uint4 w = *(const uint4*)(q + (size_t)grow * (HIDDEN / 2) + kt * 32 + k8 * 4);
      float s = sp[grow * NG1 + kt];
      float z = zp[grow * NG1 + kt];
      __half2 s2  = __float2half2_rn(s);
      __half2 nzs = __float2half2_rn(-z * s);
      uint4 o;
      o.x = dq2(w.x, s2, nzs);
      o.y = dq2(w.y, s2, nzs);
      o.z = dq2(w.z, s2, nzs);
      o.w = dq2(w.w, s2, nzs);
      int k8s = k8 ^ (row & 7);
      *(uint4*)((char*)lb + row * 128 + k8s * 16) = o;
    }
    __syncthreads();  // staging (incl. async A) complete
    // ---- compute: 2 K-steps of 32
#pragma unroll
    for (int ks = 0; ks < 2; ++ks) {
      int kc = ks * 4 + (lane >> 4);  // chunk column (8 f16 per chunk)
      f16x8 a[4], bg[2], bu[2];
#pragma unroll
      for (int im = 0; im < 4; ++im) {
        int r = wm * 64 + im * 16 + (lane & 15);
        a[im] = *(const f16x8*)((const char*)lA + r * 128 + (kc ^ (r & 7)) * 16);
      }
#pragma unroll
      for (int in_ = 0; in_ < 2; ++in_) {
        int r = wn * 32 + in_ * 16 + (lane & 15);
        bg[in_] = *(const f16x8*)((const char*)lBg + r * 128 + (kc ^ (r & 7)) * 16);
        bu[in_] = *(const f16x8*)((const char*)lBu + r * 128 + (kc ^ (r & 7)) * 16);
      }
#pragma unroll
      for (int im = 0; im < 4; ++im)
#pragma unroll
        for (int in_ = 0; in_ < 2; ++in_) {
          accg[im][in_] = __builtin_amdgcn_mfma_f32_16x16x32_f16(a[im], bg[in_], accg[im][in_], 0, 0, 0);
          accu[im][in_] = __builtin_amdgcn_mfma_f32_16x16x32_f16(a[im], bu[in_], accu[im][in_], 0, 0, 0);
        }
    }
  }
  // ---- epilogue: h = silu(g)*u, f16.  C/D: col=lane&15, row=(lane>>4)*4+r
#pragma unroll
  for (int im = 0; im < 4; ++im)
#pragma unroll
    for (int in_ = 0; in_ < 2; ++in_)
#pragma unroll
      for (int r = 0; r < 4; ++r) {
        int row = bm * 128 + wm * 64 + im * 16 + (lane >> 4) * 4 + r;
        int col = bn * 64 + wn * 32 + in_ * 16 + (lane & 15);
        float g = accg[im][in_][r];
        float u = accu[im][in_][r];
        float hv = (g / (1.0f + __expf(-g))) * u;
        h[(size_t)row * INTER + col] = (f16)hv;
      }
}

// -------------------------------------------- GEMM2: out = h Wd^T  (fp32 out)
// Block tile 128x128, 4 waves 2x2, each wave 64x64 -> 4x4 frags. LDS 32KB.
__global__ __launch_bounds__(256) void gemm_down(
    const f16* __restrict__ h, const uint32_t* __restrict__ dq_,
    const float* __restrict__ dsc, const float* __restrict__ dz,
    float* __restrict__ out) {
  __shared__ f16 lA[128 * 64];
  __shared__ f16 lB[128 * 64];
  const int tid = threadIdx.x, lane = tid & 63, wave = tid >> 6;
  const int bn = blockIdx.x, bm = blockIdx.y;  // 32 x 32
  const int wm = wave >> 1, wn = wave & 1;

  f32x4 acc[4][4] = {};

  for (int kt = 0; kt < NG2; ++kt) {
    __syncthreads();
#pragma unroll
    for (int i = 0; i < 4; ++i) {
      int c = i * 256 + tid;
      int row = c >> 3, k8 = c & 7, k8s = k8 ^ (row & 7);
      const f16* gp = h + (size_t)(bm * 128 + row) * INTER + kt * 64 + k8s * 8;
      g2lds16(gp, (char*)lA + (size_t)c * 16);
    }
#pragma unroll
    for (int i = 0; i < 4; ++i) {
      int c = i * 256 + tid;                 // 0..1023 -> 128 rows x 8 chunks
      int row = c >> 3, k8 = c & 7;
      int grow = bn * 128 + row;
      uint4 w = *(const uint4*)(dq_ + (size_t)grow * (INTER / 2) + kt * 32 + k8 * 4);
      float s = dsc[grow * NG2 + kt];
      float z = dz[grow * NG2 + kt];
      __half2 s2  = __float2half2_rn(s);
      __half2 nzs = __float2half2_rn(-z * s);
      uint4 o;
      o.x = dq2(w.x, s2, nzs);
      o.y = dq2(w.y, s2, nzs);
      o.z = dq2(w.z, s2, nzs);
      o.w = dq2(w.w, s2, nzs);
      int k8s = k8 ^ (row & 7);
      *(uint4*)((char*)lB + row * 128 + k8s * 16) = o;
    }
    __syncthreads();
#pragma unroll
    for (int ks = 0; ks < 2; ++ks) {
      int kc = ks * 4 + (lane >> 4);
      f16x8 a[4], b[4];
#pragma unroll
      for (int im = 0; im < 4; ++im) {
        int r = wm * 64 + im * 16 + (lane & 15);
        a[im] = *(const f16x8*)((const char*)lA + r * 128 + (kc ^ (r & 7)) * 16);
      }
#pragma unroll
      for (int in_ = 0; in_ < 4; ++in_) {
        int r = wn * 64 + in_ * 16 + (lane & 15);
        b[in_] = *(const f16x8*)((const char*)lB + r * 128 + (kc ^ (r & 7)) * 16);
      }
#pragma unroll
      for (int im = 0; im < 4; ++im)
#pragma unroll
        for (int in_ = 0; in_ < 4; ++in_)
          acc[im][in_] = __builtin_amdgcn_mfma_f32_16x16x32_f16(a[im], b[in_], acc[im][in_], 0, 0, 0);
    }
  }
#pragma unroll
  for (int im = 0; im < 4; ++im)
#pragma unroll
    for (int in_ = 0; in_ < 4; ++in_)
#pragma unroll
      for (int r = 0; r < 4; ++r) {
        int row = bm * 128 + wm * 64 + im * 16 + (lane >> 4) * 4 + r;
        int col = bn * 128 + wn * 64 + in_ * 16 + (lane & 15);
        out[(size_t)row * HIDDEN + col] = acc[im][in_][r];
      }
}

// ------------------------------------------------------------------- launcher
extern "C" void kernel_launch(void* const* d_in, const int* in_sizes, int n_in,
                              void* d_out, int out_size, void* d_ws, size_t ws_size,
                              hipStream_t stream) {
  const float*    x   = (const float*)d_in[0];
  const uint32_t* gq  = (const uint32_t*)d_in[1];
  const uint32_t* uq  = (const uint32_t*)d_in[2];
  const uint32_t* dqw = (const uint32_t*)d_in[3];
  const float*    gs  = (const float*)d_in[4];
  const float*    gz  = (const float*)d_in[5];
  const float*    us  = (const float*)d_in[6];
  const float*    uz  = (const float*)d_in[7];
  const float*    dsc = (const float*)d_in[8];
  const float*    dzz = (const float*)d_in[9];

  f16* xh   = (f16*)d_ws;                                        // 32 MB
  f16* hbuf = (f16*)((char*)d_ws + (size_t)NTOK * HIDDEN * 2);   // 86 MB
  float* out = (float*)d_out;

  cvt_x<<<dim3((NTOK * HIDDEN) / (256 * 8)), 256, 0, stream>>>(x, xh);
  gemm_gateup<<<dim3(INTER / 64, NTOK / 128), 256, 0, stream>>>(
      xh, gq, uq, gs, gz, us, uz, hbuf);
  gemm_down<<<dim3(HIDDEN / 128, NTOK / 128), 256, 0, stream>>>(
      hbuf, dqw, dsc, dzz, out);
}

// Round 2
// 1548.495 us; speedup vs baseline: 1.4805x; 1.4805x over previous
//
#include <hip/hip_runtime.h>
#include <hip/hip_fp16.h>
#include <cstdint>
#include <cstddef>

// Problem constants (fixed by the reference)
#define HIDDEN 4096
#define INTER  11008
#define NTOK   4096          // B*S = 4*1024
#define NG1    (HIDDEN/64)   // 64 groups along hidden
#define NG2    (INTER/64)    // 172 groups along inter

typedef _Float16 f16;
typedef _Float16 f16x8 __attribute__((ext_vector_type(8)));
typedef float    f32x4 __attribute__((ext_vector_type(4)));

// ---- async global->LDS, 16B per lane (dest must be wave-uniform base + lane*16)
__device__ __forceinline__ void g2lds16(const void* g, void* l) {
  __builtin_amdgcn_global_load_lds(
      (const __attribute__((address_space(1))) uint32_t*)g,
      (__attribute__((address_space(3))) uint32_t*)l, 16, 0, 0);
}

// ---- dequant one storage int32 (value in [0,256) = 2 nibbles) -> 2 f16
// w = (q - z) * s via exact f16 exponent trick + single pk_fma.
__device__ __forceinline__ uint32_t dq2(uint32_t b, __half2 s2, __half2 nzs) {
  uint32_t qb = 0x64006400u | (b >> 4) | ((b & 0xFu) << 16);
  __half2 hq = __builtin_bit_cast(__half2, qb);
  __half2 t  = __hsub2(hq, __builtin_bit_cast(__half2, 0x64006400u));
  __half2 wv = __hfma2(t, s2, nzs);
  return __builtin_bit_cast(uint32_t, wv);
}

// ---------------------------------------------------------------- x: fp32->f16
__global__ __launch_bounds__(256) void cvt_x(const float* __restrict__ x,
                                             f16* __restrict__ xh) {
  size_t i = ((size_t)blockIdx.x * 256 + threadIdx.x) * 8;
  float4 a = *(const float4*)(x + i);
  float4 b = *(const float4*)(x + i + 4);
  f16x8 o = {(f16)a.x, (f16)a.y, (f16)a.z, (f16)a.w,
             (f16)b.x, (f16)b.y, (f16)b.z, (f16)b.w};
  *(f16x8*)(xh + i) = o;
}

// -------------------------------------------- GEMM1: h = silu(x Wg^T) * (x Wu^T)
// Block tile: 256 (M) x 64 (N) dual (gate+up share A). 512 threads = 8 waves,
// wave-tile 64x64 (64 M x 32+32 N). BK=64 = one quant group.
// LDS: A 32KB + Bg 8KB + Bu 8KB = 48KB -> 3 blocks/CU.
// Grid: blockIdx.x = bm (fast) so consecutive blocks share WEIGHTS in L2;
// A (32 MB) is L3-resident.
__global__ __launch_bounds__(512) void gemm_gateup(
    const f16* __restrict__ xh,
    const uint32_t* __restrict__ gq, const uint32_t* __restrict__ uq,
    const float* __restrict__ gs, const float* __restrict__ gz,
    const float* __restrict__ us, const float* __restrict__ uz,
    f16* __restrict__ h) {
  __shared__ f16 lA[256 * 64];
  __shared__ f16 lBg[64 * 64];
  __shared__ f16 lBu[64 * 64];
  const int tid = threadIdx.x, lane = tid & 63, wave = tid >> 6;
  const int bm = blockIdx.x, bn = blockIdx.y;      // bm<16, bn<172
  const int wm = wave >> 1, wn = wave & 1;

  // ---- hoisted A staging addressing: 4 chunks/thread, rows i*64 + (tid>>3)
  const int arow0 = tid >> 3;
  const int ak8s  = (tid & 7) ^ (arow0 & 7);        // (i*64+row0)&7 == row0&7
  const f16* aptr = xh + (size_t)(bm * 256 + arow0) * HIDDEN + ak8s * 8;
  char* aldst = (char*)lA + tid * 16;               // + i*512*16

  // ---- hoisted B staging addressing: 2 chunks/thread (rows t>>3 and 32+(t>>3))
  const int mat = tid >> 8;                         // 0 = gate, 1 = up (wave-uniform)
  const int t = tid & 255;
  const int brow0 = t >> 3;
  const uint32_t* qp = (mat ? uq : gq) + (size_t)(bn * 64 + brow0) * (HIDDEN / 2) + (t & 7) * 4;
  const float* sp = (mat ? us : gs) + (size_t)(bn * 64 + brow0) * NG1;
  const float* zp = (mat ? uz : gz) + (size_t)(bn * 64 + brow0) * NG1;
  char* lb = (char*)(mat ? lBu : lBg);
  const int bws0 = brow0 * 128 + (((t & 7) ^ (brow0 & 7)) << 4);  // byte off, j=0
  // j=1 row = brow0+32: (row&7) unchanged -> same xor, +32*128 bytes

  // ---- hoisted fragment-read addressing
  int abase[4], asel[4];
#pragma unroll
  for (int im = 0; im < 4; ++im) {
    int r = wm * 64 + im * 16 + (lane & 15);
    abase[im] = r * 128; asel[im] = r & 7;
  }
  int bbase[2], bsel[2];
#pragma unroll
  for (int in_ = 0; in_ < 2; ++in_) {
    int r = wn * 32 + in_ * 16 + (lane & 15);
    bbase[in_] = r * 128; bsel[in_] = r & 7;
  }
  const int kchunk = lane >> 4;

  f32x4 accg[4][2] = {};
  f32x4 accu[4][2] = {};

  for (int kt = 0; kt < NG1; ++kt) {
    __syncthreads();  // previous tile fully consumed
    // ---- A staging (async DMA, 16B/lane)
#pragma unroll
    for (int i = 0; i < 4; ++i)
      g2lds16(aptr + (size_t)i * 64 * HIDDEN, aldst + i * 512 * 16);
    // ---- B staging + dequant (2 rows per thread)
    {
      uint4 w0 = *(const uint4*)qp;
      uint4 w1 = *(const uint4*)(qp + (size_t)32 * (HIDDEN / 2));
      float s0f = sp[kt], z0f = zp[kt];
      float s1f = sp[32 * NG1 + kt], z1f = zp[32 * NG1 + kt];
      __half2 s0 = __float2half2_rn(s0f), n0 = __float2half2_rn(-z0f * s0f);
      __half2 s1 = __float2half2_rn(s1f), n1 = __float2half2_rn(-z1f * s1f);
      uint4 o0, o1;
      o0.x = dq2(w0.x, s0, n0); o0.y = dq2(w0.y, s0, n0);
      o0.z = dq2(w0.z, s0, n0); o0.w = dq2(w0.w, s0, n0);
      o1.x = dq2(w1.x, s1, n1); o1.y = dq2(w1.y, s1, n1);
      o1.z = dq2(w1.z, s1, n1); o1.w = dq2(w1.w, s1, n1);
      *(uint4*)(lb + bws0) = o0;
      *(uint4*)(lb + bws0 + 32 * 128) = o1;
    }
    __syncthreads();  // staging (incl. async A) complete
    // ---- compute: 2 K-steps of 32
#pragma unroll
    for (int ks = 0; ks < 2; ++ks) {
      int kc = ks * 4 + kchunk;
      f16x8 a[4], bg[2], bu[2];
#pragma unroll
      for (int im = 0; im < 4; ++im)
        a[im] = *(const f16x8*)((const char*)lA + abase[im] + ((kc ^ asel[im]) << 4));
#pragma unroll
      for (int in_ = 0; in_ < 2; ++in_) {
        bg[in_] = *(const f16x8*)((const char*)lBg + bbase[in_] + ((kc ^ bsel[in_]) << 4));
        bu[in_] = *(const f16x8*)((const char*)lBu + bbase[in_] + ((kc ^ bsel[in_]) << 4));
      }
#pragma unroll
      for (int im = 0; im < 4; ++im)
#pragma unroll
        for (int in_ = 0; in_ < 2; ++in_) {
          accg[im][in_] = __builtin_amdgcn_mfma_f32_16x16x32_f16(a[im], bg[in_], accg[im][in_], 0, 0, 0);
          accu[im][in_] = __builtin_amdgcn_mfma_f32_16x16x32_f16(a[im], bu[in_], accu[im][in_], 0, 0, 0);
        }
    }
    aptr += 64;       // next K-tile
    qp += 32;
  }
  // ---- epilogue: h = silu(g)*u, f16.  C/D: col=lane&15, row=(lane>>4)*4+r
#pragma unroll
  for (int im = 0; im < 4; ++im)
#pragma unroll
    for (int in_ = 0; in_ < 2; ++in_)
#pragma unroll
      for (int r = 0; r < 4; ++r) {
        int row = bm * 256 + wm * 64 + im * 16 + (lane >> 4) * 4 + r;
        int col = bn * 64 + wn * 32 + in_ * 16 + (lane & 15);
        float g = accg[im][in_][r];
        float u = accu[im][in_][r];
        float hv = (g / (1.0f + __expf(-g))) * u;
        h[(size_t)row * INTER + col] = (f16)hv;
      }
}

// -------------------------------------------- GEMM2: out = h Wd^T  (fp32 out)
// Block tile 256x128, 512 threads = 8 waves, wave-tile 64x64. LDS 48KB.
__global__ __launch_bounds__(512) void gemm_down(
    const f16* __restrict__ h, const uint32_t* __restrict__ dq_,
    const float* __restrict__ dsc, const float* __restrict__ dz,
    float* __restrict__ out) {
  __shared__ f16 lA[256 * 64];
  __shared__ f16 lB[128 * 64];
  const int tid = threadIdx.x, lane = tid & 63, wave = tid >> 6;
  const int bm = blockIdx.x, bn = blockIdx.y;  // 16 x 32
  const int wm = wave >> 1, wn = wave & 1;

  const int arow0 = tid >> 3;
  const int ak8s  = (tid & 7) ^ (arow0 & 7);
  const f16* aptr = h + (size_t)(bm * 256 + arow0) * INTER + ak8s * 8;
  char* aldst = (char*)lA + tid * 16;

  // B staging: 1024 chunks (128 rows x 8), 2/thread, rows tid>>3 and 64+(tid>>3)
  const int brow0 = tid >> 3;                       // 0..63
  const uint32_t* qp = dq_ + (size_t)(bn * 128 + brow0) * (INTER / 2) + (tid & 7) * 4;
  const float* sp = dsc + (size_t)(bn * 128 + brow0) * NG2;
  const float* zp = dz + (size_t)(bn * 128 + brow0) * NG2;
  const int bws0 = brow0 * 128 + (((tid & 7) ^ (brow0 & 7)) << 4);
  // j=1 row = brow0+64: (row&7) unchanged, +64*128 bytes

  int abase[4], asel[4];
#pragma unroll
  for (int im = 0; im < 4; ++im) {
    int r = wm * 64 + im * 16 + (lane & 15);
    abase[im] = r * 128; asel[im] = r & 7;
  }
  int bbase[4], bsel[4];
#pragma unroll
  for (int in_ = 0; in_ < 4; ++in_) {
    int r = wn * 64 + in_ * 16 + (lane & 15);
    bbase[in_] = r * 128; bsel[in_] = r & 7;
  }
  const int kchunk = lane >> 4;

  f32x4 acc[4][4] = {};

  for (int kt = 0; kt < NG2; ++kt) {
    __syncthreads();
#pragma unroll
    for (int i = 0; i < 4; ++i)
      g2lds16(aptr + (size_t)i * 64 * INTER, aldst + i * 512 * 16);
    {
      uint4 w0 = *(const uint4*)qp;
      uint4 w1 = *(const uint4*)(qp + (size_t)64 * (INTER / 2));
      float s0f = sp[kt], z0f = zp[kt];
      float s1f = sp[64 * NG2 + kt], z1f = zp[64 * NG2 + kt];
      __half2 s0 = __float2half2_rn(s0f), n0 = __float2half2_rn(-z0f * s0f);
      __half2 s1 = __float2half2_rn(s1f), n1 = __float2half2_rn(-z1f * s1f);
      uint4 o0, o1;
      o0.x = dq2(w0.x, s0, n0); o0.y = dq2(w0.y, s0, n0);
      o0.z = dq2(w0.z, s0, n0); o0.w = dq2(w0.w, s0, n0);
      o1.x = dq2(w1.x, s1, n1); o1.y = dq2(w1.y, s1, n1);
      o1.z = dq2(w1.z, s1, n1); o1.w = dq2(w1.w, s1, n1);
      *(uint4*)((char*)lB + bws0) = o0;
      *(uint4*)((char*)lB + bws0 + 64 * 128) = o1;
    }
    __syncthreads();
#pragma unroll
    for (int ks = 0; ks < 2; ++ks) {
      int kc = ks * 4 + kchunk;
      f16x8 a[4], b[4];
#pragma unroll
      for (int im = 0; im < 4; ++im)
        a[im] = *(const f16x8*)((const char*)lA + abase[im] + ((kc ^ asel[im]) << 4));
#pragma unroll
      for (int in_ = 0; in_ < 4; ++in_)
        b[in_] = *(const f16x8*)((const char*)lB + bbase[in_] + ((kc ^ bsel[in_]) << 4));
#pragma unroll
      for (int im = 0; im < 4; ++im)
#pragma unroll
        for (int in_ = 0; in_ < 4; ++in_)
          acc[im][in_] = __builtin_amdgcn_mfma_f32_16x16x32_f16(a[im], b[in_], acc[im][in_], 0, 0, 0);
    }
    aptr += 64;
    qp += 32;
  }
#pragma unroll
  for (int im = 0; im < 4; ++im)
#pragma unroll
    for (int in_ = 0; in_ < 4; ++in_)
#pragma unroll
      for (int r = 0; r < 4; ++r) {
        int row = bm * 256 + wm * 64 + im * 16 + (lane >> 4) * 4 + r;
        int col = bn * 128 + wn * 64 + in_ * 16 + (lane & 15);
        out[(size_t)row * HIDDEN + col] = acc[im][in_][r];
      }
}

// ------------------------------------------------------------------- launcher
extern "C" void kernel_launch(void* const* d_in, const int* in_sizes, int n_in,
                              void* d_out, int out_size, void* d_ws, size_t ws_size,
                              hipStream_t stream) {
  const float*    x   = (const float*)d_in[0];
  const uint32_t* gq  = (const uint32_t*)d_in[1];
  const uint32_t* uq  = (const uint32_t*)d_in[2];
  const uint32_t* dqw = (const uint32_t*)d_in[3];
  const float*    gs  = (const float*)d_in[4];
  const float*    gz  = (const float*)d_in[5];
  const float*    us  = (const float*)d_in[6];
  const float*    uz  = (const float*)d_in[7];
  const float*    dsc = (const float*)d_in[8];
  const float*    dzz = (const float*)d_in[9];

  f16* xh   = (f16*)d_ws;                                        // 32 MB
  f16* hbuf = (f16*)((char*)d_ws + (size_t)NTOK * HIDDEN * 2);   // 90 MB
  float* out = (float*)d_out;

  cvt_x<<<dim3((NTOK * HIDDEN) / (256 * 8)), 256, 0, stream>>>(x, xh);
  gemm_gateup<<<dim3(NTOK / 256, INTER / 64), 512, 0, stream>>>(
      xh, gq, uq, gs, gz, us, uz, hbuf);
  gemm_down<<<dim3(NTOK / 256, HIDDEN / 128), 512, 0, stream>>>(
      hbuf, dqw, dsc, dzz, out);
}

// Round 3
// 1519.337 us; speedup vs baseline: 1.5089x; 1.0192x over previous
//
#include <hip/hip_runtime.h>
#include <hip/hip_fp16.h>
#include <cstdint>
#include <cstddef>

// Problem constants (fixed by the reference)
#define HIDDEN 4096
#define INTER  11008
#define NTOK   4096          // B*S = 4*1024
#define NG1    (HIDDEN/64)   // 64 groups along hidden
#define NG2    (INTER/64)    // 172 groups along inter

typedef _Float16 f16;
typedef _Float16 f16x8 __attribute__((ext_vector_type(8)));
typedef float    f32x4 __attribute__((ext_vector_type(4)));

// ---- async global->LDS, 16B per lane (dest must be wave-uniform base + lane*16)
__device__ __forceinline__ void g2lds16(const void* g, void* l) {
  __builtin_amdgcn_global_load_lds(
      (const __attribute__((address_space(1))) uint32_t*)g,
      (__attribute__((address_space(3))) uint32_t*)l, 16, 0, 0);
}

// ---- dequant one storage int32 (value in [0,256) = 2 nibbles) -> 2 f16
// w = (q - z) * s via exact f16 exponent trick + single pk_fma.
__device__ __forceinline__ uint32_t dq2(uint32_t b, __half2 s2, __half2 nzs) {
  uint32_t qb = 0x64006400u | (b >> 4) | ((b & 0xFu) << 16);
  __half2 hq = __builtin_bit_cast(__half2, qb);
  __half2 t  = __hsub2(hq, __builtin_bit_cast(__half2, 0x64006400u));
  __half2 wv = __hfma2(t, s2, nzs);
  return __builtin_bit_cast(uint32_t, wv);
}

// ---------------------------------------------------------------- x: fp32->f16
__global__ __launch_bounds__(256) void cvt_x(const float* __restrict__ x,
                                             f16* __restrict__ xh) {
  size_t i = ((size_t)blockIdx.x * 256 + threadIdx.x) * 8;
  float4 a = *(const float4*)(x + i);
  float4 b = *(const float4*)(x + i + 4);
  f16x8 o = {(f16)a.x, (f16)a.y, (f16)a.z, (f16)a.w,
             (f16)b.x, (f16)b.y, (f16)b.z, (f16)b.w};
  *(f16x8*)(xh + i) = o;
}

// -------------------------------------------- GEMM1: h = silu(x Wg^T) * (x Wu^T)
// Block 256M x 64N dual, 8 waves (wave tile 64 x 32+32), BK=64 = 1 quant group.
// PIPELINED: A double-buffered (async DMA issued BEFORE compute of prior tile),
// B packed+scales prefetched to regs before compute, dequant+LDS-write between
// the two barriers. Barrier (a) drains loads that flew during compute; barrier
// (b) waits only on LDS writes. LDS = 2*32K (A) + 8K+8K (B) = 80 KB dynamic.
__global__ __launch_bounds__(512, 4) void gemm_gateup(
    const f16* __restrict__ xh,
    const uint32_t* __restrict__ gq, const uint32_t* __restrict__ uq,
    const float* __restrict__ gs, const float* __restrict__ gz,
    const float* __restrict__ us, const float* __restrict__ uz,
    f16* __restrict__ h) {
  extern __shared__ char smem[];
  f16* lA0 = (f16*)smem;                 // 32 KB
  f16* lA1 = (f16*)(smem + 32768);       // 32 KB
  char* lBg = smem + 65536;              // 8 KB
  char* lBu = smem + 73728;              // 8 KB
  const int tid = threadIdx.x, lane = tid & 63, wave = tid >> 6;
  const int bm = blockIdx.x, bn = blockIdx.y;      // bm<16, bn<172
  const int wm = wave >> 1, wn = wave & 1;

  // ---- A staging addressing: 4 chunks/thread, rows i*64 + (tid>>3)
  const int arow0 = tid >> 3;
  const int ak8s  = (tid & 7) ^ (arow0 & 7);
  const f16* aptr = xh + (size_t)(bm * 256 + arow0) * HIDDEN + ak8s * 8;
  const int aoff = tid * 16;             // + i*8192 per chunk

  // ---- B staging addressing: 2 rows/thread of one matrix
  const int mat = tid >> 8;              // 0 = gate, 1 = up (wave-uniform)
  const int t = tid & 255;
  const int brow0 = t >> 3;
  const uint32_t* qp = (mat ? uq : gq) + (size_t)(bn * 64 + brow0) * (HIDDEN / 2) + (t & 7) * 4;
  const float* sp = (mat ? us : gs) + (size_t)(bn * 64 + brow0) * NG1;
  const float* zp = (mat ? uz : gz) + (size_t)(bn * 64 + brow0) * NG1;
  char* lb = mat ? lBu : lBg;
  const int bws0 = brow0 * 128 + (((t & 7) ^ (brow0 & 7)) << 4);

  // ---- fragment-read addressing
  int abase[4], asel[4];
#pragma unroll
  for (int im = 0; im < 4; ++im) {
    int r = wm * 64 + im * 16 + (lane & 15);
    abase[im] = r * 128; asel[im] = r & 7;
  }
  int bbase[2], bsel[2];
#pragma unroll
  for (int in_ = 0; in_ < 2; ++in_) {
    int r = wn * 32 + in_ * 16 + (lane & 15);
    bbase[in_] = r * 128; bsel[in_] = r & 7;
  }
  const int kchunk = lane >> 4;

  f32x4 accg[4][2] = {};
  f32x4 accu[4][2] = {};

  auto stageA = [&](const f16* src, f16* dst) {
#pragma unroll
    for (int i = 0; i < 4; ++i)
      g2lds16(src + (size_t)i * 64 * HIDDEN, (char*)dst + aoff + i * 8192);
  };
  auto loadB = [&](int ktn, uint4& w0, uint4& w1,
                   float& s0f, float& z0f, float& s1f, float& z1f) {
    w0 = *(const uint4*)(qp + (size_t)ktn * 32);
    w1 = *(const uint4*)(qp + (size_t)32 * (HIDDEN / 2) + (size_t)ktn * 32);
    s0f = sp[ktn]; z0f = zp[ktn];
    s1f = sp[32 * NG1 + ktn]; z1f = zp[32 * NG1 + ktn];
  };
  auto writeB = [&](uint4 w0, uint4 w1, float s0f, float z0f, float s1f, float z1f) {
    __half2 s0 = __float2half2_rn(s0f), n0 = __float2half2_rn(-z0f * s0f);
    __half2 s1 = __float2half2_rn(s1f), n1 = __float2half2_rn(-z1f * s1f);
    uint4 o0, o1;
    o0.x = dq2(w0.x, s0, n0); o0.y = dq2(w0.y, s0, n0);
    o0.z = dq2(w0.z, s0, n0); o0.w = dq2(w0.w, s0, n0);
    o1.x = dq2(w1.x, s1, n1); o1.y = dq2(w1.y, s1, n1);
    o1.z = dq2(w1.z, s1, n1); o1.w = dq2(w1.w, s1, n1);
    *(uint4*)(lb + bws0) = o0;
    *(uint4*)(lb + bws0 + 32 * 128) = o1;
  };
  auto compute = [&](const f16* lA) {
#pragma unroll
    for (int ks = 0; ks < 2; ++ks) {
      int kc = ks * 4 + kchunk;
      f16x8 a[4], bg[2], bu[2];
#pragma unroll
      for (int im = 0; im < 4; ++im)
        a[im] = *(const f16x8*)((const char*)lA + abase[im] + ((kc ^ asel[im]) << 4));
#pragma unroll
      for (int in_ = 0; in_ < 2; ++in_) {
        bg[in_] = *(const f16x8*)(lBg + bbase[in_] + ((kc ^ bsel[in_]) << 4));
        bu[in_] = *(const f16x8*)(lBu + bbase[in_] + ((kc ^ bsel[in_]) << 4));
      }
#pragma unroll
      for (int im = 0; im < 4; ++im)
#pragma unroll
        for (int in_ = 0; in_ < 2; ++in_) {
          accg[im][in_] = __builtin_amdgcn_mfma_f32_16x16x32_f16(a[im], bg[in_], accg[im][in_], 0, 0, 0);
          accu[im][in_] = __builtin_amdgcn_mfma_f32_16x16x32_f16(a[im], bu[in_], accu[im][in_], 0, 0, 0);
        }
    }
  };

  // ---- prologue: tile 0 fully staged (latency exposed once)
  stageA(aptr, lA0);
  {
    uint4 w0, w1; float s0f, z0f, s1f, z1f;
    loadB(0, w0, w1, s0f, z0f, s1f, z1f);
    writeB(w0, w1, s0f, z0f, s1f, z1f);
  }
  __syncthreads();

  // ---- pipelined main loop
  for (int kt = 0; kt < NG1 - 1; ++kt) {
    stageA(aptr + (size_t)(kt + 1) * 64, (kt & 1) ? lA0 : lA1);  // A(kt+1)
    uint4 w0, w1; float s0f, z0f, s1f, z1f;
    loadB(kt + 1, w0, w1, s0f, z0f, s1f, z1f);                   // B(kt+1) -> regs
    compute((kt & 1) ? lA1 : lA0);                               // tile kt
    __syncthreads();   // (a) drains A(kt+1)/B(kt+1) loads (flew during compute)
    writeB(w0, w1, s0f, z0f, s1f, z1f);                          // B(kt+1) -> LDS
    __syncthreads();   // (b) lgkm only
  }
  compute(((NG1 - 1) & 1) ? lA1 : lA0);

  // ---- epilogue: h = silu(g)*u, f16.  C/D: col=lane&15, row=(lane>>4)*4+r
#pragma unroll
  for (int im = 0; im < 4; ++im)
#pragma unroll
    for (int in_ = 0; in_ < 2; ++in_)
#pragma unroll
      for (int r = 0; r < 4; ++r) {
        int row = bm * 256 + wm * 64 + im * 16 + (lane >> 4) * 4 + r;
        int col = bn * 64 + wn * 32 + in_ * 16 + (lane & 15);
        float g = accg[im][in_][r];
        float u = accu[im][in_][r];
        float hv = (g / (1.0f + __expf(-g))) * u;
        h[(size_t)row * INTER + col] = (f16)hv;
      }
}

// -------------------------------------------- GEMM2: out = h Wd^T  (fp32 out)
// Block 256x128, 8 waves (wave tile 64x64), same pipelined structure.
// LDS = 2*32K (A) + 16K (B) = 80 KB dynamic.
__global__ __launch_bounds__(512, 4) void gemm_down(
    const f16* __restrict__ h, const uint32_t* __restrict__ dq_,
    const float* __restrict__ dsc, const float* __restrict__ dz,
    float* __restrict__ out) {
  extern __shared__ char smem[];
  f16* lA0 = (f16*)smem;
  f16* lA1 = (f16*)(smem + 32768);
  char* lB = smem + 65536;               // 16 KB
  const int tid = threadIdx.x, lane = tid & 63, wave = tid >> 6;
  const int bm = blockIdx.x, bn = blockIdx.y;  // 16 x 32
  const int wm = wave >> 1, wn = wave & 1;

  const int arow0 = tid >> 3;
  const int ak8s  = (tid & 7) ^ (arow0 & 7);
  const f16* aptr = h + (size_t)(bm * 256 + arow0) * INTER + ak8s * 8;
  const int aoff = tid * 16;

  const int brow0 = tid >> 3;                       // 0..63, rows brow0 & brow0+64
  const uint32_t* qp = dq_ + (size_t)(bn * 128 + brow0) * (INTER / 2) + (tid & 7) * 4;
  const float* sp = dsc + (size_t)(bn * 128 + brow0) * NG2;
  const float* zp = dz + (size_t)(bn * 128 + brow0) * NG2;
  const int bws0 = brow0 * 128 + (((tid & 7) ^ (brow0 & 7)) << 4);

  int abase[4], asel[4];
#pragma unroll
  for (int im = 0; im < 4; ++im) {
    int r = wm * 64 + im * 16 + (lane & 15);
    abase[im] = r * 128; asel[im] = r & 7;
  }
  int bbase[4], bsel[4];
#pragma unroll
  for (int in_ = 0; in_ < 4; ++in_) {
    int r = wn * 64 + in_ * 16 + (lane & 15);
    bbase[in_] = r * 128; bsel[in_] = r & 7;
  }
  const int kchunk = lane >> 4;

  f32x4 acc[4][4] = {};

  auto stageA = [&](const f16* src, f16* dst) {
#pragma unroll
    for (int i = 0; i < 4; ++i)
      g2lds16(src + (size_t)i * 64 * INTER, (char*)dst + aoff + i * 8192);
  };
  auto loadB = [&](int ktn, uint4& w0, uint4& w1,
                   float& s0f, float& z0f, float& s1f, float& z1f) {
    w0 = *(const uint4*)(qp + (size_t)ktn * 32);
    w1 = *(const uint4*)(qp + (size_t)64 * (INTER / 2) + (size_t)ktn * 32);
    s0f = sp[ktn]; z0f = zp[ktn];
    s1f = sp[64 * NG2 + ktn]; z1f = zp[64 * NG2 + ktn];
  };
  auto writeB = [&](uint4 w0, uint4 w1, float s0f, float z0f, float s1f, float z1f) {
    __half2 s0 = __float2half2_rn(s0f), n0 = __float2half2_rn(-z0f * s0f);
    __half2 s1 = __float2half2_rn(s1f), n1 = __float2half2_rn(-z1f * s1f);
    uint4 o0, o1;
    o0.x = dq2(w0.x, s0, n0); o0.y = dq2(w0.y, s0, n0);
    o0.z = dq2(w0.z, s0, n0); o0.w = dq2(w0.w, s0, n0);
    o1.x = dq2(w1.x, s1, n1); o1.y = dq2(w1.y, s1, n1);
    o1.z = dq2(w1.z, s1, n1); o1.w = dq2(w1.w, s1, n1);
    *(uint4*)(lB + bws0) = o0;
    *(uint4*)(lB + bws0 + 64 * 128) = o1;
  };
  auto compute = [&](const f16* lA) {
#pragma unroll
    for (int ks = 0; ks < 2; ++ks) {
      int kc = ks * 4 + kchunk;
      f16x8 a[4], b[4];
#pragma unroll
      for (int im = 0; im < 4; ++im)
        a[im] = *(const f16x8*)((const char*)lA + abase[im] + ((kc ^ asel[im]) << 4));
#pragma unroll
      for (int in_ = 0; in_ < 4; ++in_)
        b[in_] = *(const f16x8*)(lB + bbase[in_] + ((kc ^ bsel[in_]) << 4));
#pragma unroll
      for (int im = 0; im < 4; ++im)
#pragma unroll
        for (int in_ = 0; in_ < 4; ++in_)
          acc[im][in_] = __builtin_amdgcn_mfma_f32_16x16x32_f16(a[im], b[in_], acc[im][in_], 0, 0, 0);
    }
  };

  stageA(aptr, lA0);
  {
    uint4 w0, w1; float s0f, z0f, s1f, z1f;
    loadB(0, w0, w1, s0f, z0f, s1f, z1f);
    writeB(w0, w1, s0f, z0f, s1f, z1f);
  }
  __syncthreads();

  for (int kt = 0; kt < NG2 - 1; ++kt) {
    stageA(aptr + (size_t)(kt + 1) * 64, (kt & 1) ? lA0 : lA1);
    uint4 w0, w1; float s0f, z0f, s1f, z1f;
    loadB(kt + 1, w0, w1, s0f, z0f, s1f, z1f);
    compute((kt & 1) ? lA1 : lA0);
    __syncthreads();
    writeB(w0, w1, s0f, z0f, s1f, z1f);
    __syncthreads();
  }
  compute(((NG2 - 1) & 1) ? lA1 : lA0);

#pragma unroll
  for (int im = 0; im < 4; ++im)
#pragma unroll
    for (int in_ = 0; in_ < 4; ++in_)
#pragma unroll
      for (int r = 0; r < 4; ++r) {
        int row = bm * 256 + wm * 64 + im * 16 + (lane >> 4) * 4 + r;
        int col = bn * 128 + wn * 64 + in_ * 16 + (lane & 15);
        out[(size_t)row * HIDDEN + col] = acc[im][in_][r];
      }
}

// ------------------------------------------------------------------- launcher
extern "C" void kernel_launch(void* const* d_in, const int* in_sizes, int n_in,
                              void* d_out, int out_size, void* d_ws, size_t ws_size,
                              hipStream_t stream) {
  const float*    x   = (const float*)d_in[0];
  const uint32_t* gq  = (const uint32_t*)d_in[1];
  const uint32_t* uq  = (const uint32_t*)d_in[2];
  const uint32_t* dqw = (const uint32_t*)d_in[3];
  const float*    gs  = (const float*)d_in[4];
  const float*    gz  = (const float*)d_in[5];
  const float*    us  = (const float*)d_in[6];
  const float*    uz  = (const float*)d_in[7];
  const float*    dsc = (const float*)d_in[8];
  const float*    dzz = (const float*)d_in[9];

  f16* xh   = (f16*)d_ws;                                        // 32 MB
  f16* hbuf = (f16*)((char*)d_ws + (size_t)NTOK * HIDDEN * 2);   // 90 MB
  float* out = (float*)d_out;

  const int LDS_BYTES = 80 * 1024;
  (void)hipFuncSetAttribute((const void*)gemm_gateup,
                            hipFuncAttributeMaxDynamicSharedMemorySize, LDS_BYTES);
  (void)hipFuncSetAttribute((const void*)gemm_down,
                            hipFuncAttributeMaxDynamicSharedMemorySize, LDS_BYTES);

  cvt_x<<<dim3((NTOK * HIDDEN) / (256 * 8)), 256, 0, stream>>>(x, xh);
  gemm_gateup<<<dim3(NTOK / 256, INTER / 64), 512, LDS_BYTES, stream>>>(
      xh, gq, uq, gs, gz, us, uz, hbuf);
  gemm_down<<<dim3(NTOK / 256, HIDDEN / 128), 512, LDS_BYTES, stream>>>(
      hbuf, dqw, dsc, dzz, out);
}